// Round 8
// baseline (237.111 us; speedup 1.0000x reference)
//
#include <hip/hip_runtime.h>

// ---------------------------------------------------------------------------
// GCN: 3-layer, N=50000 nodes, E=800000 edges, F_IN=128, H=128, C=64.
//   norm[e] = dinv[src]*dinv[dst]  =>  fold dinv into GEMM epilogue and
//   aggregation epilogue.  Self-loop = + g[i].
//   layer: g = dinv .* (A @ W);  h = act(dinv[i]*(g[i] + sum_{j->i} g[j]) + b)
// R2: hierarchical scan. R3: G bf16. R4: bucketed counting-sort graph build.
// R5: MFMA GEMMs (16x16x32 bf16), bf16 feature path, XOR-swizzled LDS.
// R6: 8-deep gather unroll. R7: 16-deep predicated (REGRESSED: VALU+waste).
// R8: agg restructured to 16-lane groups -> 4 nodes/wave, 8-deep per group
//     = 32 independent gathers in flight per wave (4x MLP), 16B/lane loads,
//     exact 8-batches + one clamped tail batch. launch_bounds(512,8).
// ---------------------------------------------------------------------------

#define NODES_PER_BUCKET 1024      // bucket = dst >> 10
#define MAX_BUCKETS 64             // n <= 64K nodes (50000 -> 49 buckets)
#define CVT_BLOCKS 160             // 40960 weight elems / 256

typedef __attribute__((ext_vector_type(8))) short short8;
typedef __attribute__((ext_vector_type(4))) float f32x4;

__device__ inline unsigned bf16_rn(float x) {          // rne, no NaN expected
    unsigned u = __float_as_uint(x);
    return (u + 0x7fffu + ((u >> 16) & 1u)) >> 16;
}
__device__ inline float bf_lo(unsigned u) { return __uint_as_float(u << 16); }
__device__ inline float bf_hi(unsigned u) { return __uint_as_float(u & 0xffff0000u); }

// ---------------------------------------------------------------------------
// prep_k: blocks [0,CVT_BLOCKS) convert W0|W1|W2 f32 -> bf16 Wt[out][128];
//         remaining blocks build the 64-bucket dst histogram.
// ---------------------------------------------------------------------------
__global__ __launch_bounds__(256) void prep_k(const int* __restrict__ dst, int e,
                                              int* __restrict__ bcnt,
                                              const float* __restrict__ W0,
                                              const float* __restrict__ W1,
                                              const float* __restrict__ W2,
                                              unsigned short* __restrict__ Wt) {
    const int t = threadIdx.x;
    if (blockIdx.x < CVT_BLOCKS) {
        int id = blockIdx.x * 256 + t;              // 0 .. 40959
        const float* W;
        int out, loc;
        if (id < 16384)      { W = W0; out = 128; loc = id; }
        else if (id < 32768) { W = W1; out = 128; loc = id - 16384; }
        else                 { W = W2; out = 64;  loc = id - 32768; }
        int o = loc >> 7, k = loc & 127;
        Wt[id] = (unsigned short)bf16_rn(W[k * out + o]);
        return;
    }
    __shared__ int h[MAX_BUCKETS];
    if (t < MAX_BUCKETS) h[t] = 0;
    __syncthreads();
    const int i0 = (blockIdx.x - CVT_BLOCKS) * 4096;
#pragma unroll
    for (int k = 0; k < 16; ++k) {
        int i = i0 + t + k * 256;
        if (i < e) atomicAdd(&h[dst[i] >> 10], 1);
    }
    __syncthreads();
    if (t < MAX_BUCKETS && h[t]) atomicAdd(&bcnt[t], h[t]);
}

// ---------------------------------------------------------------------------
// scatter_k: block-chunked pair scatter into bucket segments.
// ---------------------------------------------------------------------------
__global__ __launch_bounds__(512) void scatter_k(const int* __restrict__ src,
                                                 const int* __restrict__ dst,
                                                 int e,
                                                 const int* __restrict__ bcnt,
                                                 int* __restrict__ scur,
                                                 uint2* __restrict__ pairs) {
    __shared__ int bbase_s[MAX_BUCKETS];
    __shared__ int cnt[MAX_BUCKETS];
    __shared__ int cur[MAX_BUCKETS];
    __shared__ int gb[MAX_BUCKETS];
    const int t = threadIdx.x;
    if (t < MAX_BUCKETS) {
        int v = bcnt[t];                        // zeros beyond nbuck
        int x = v;
#pragma unroll
        for (int off = 1; off < 64; off <<= 1) {
            int y = __shfl_up(x, off);
            if ((t & 63) >= off) x += y;
        }
        bbase_s[t] = x - v;                     // exclusive scan
        cnt[t] = 0;
    }
    __syncthreads();
    const int i0 = blockIdx.x * 8192;
    int d[16];
#pragma unroll
    for (int k = 0; k < 16; ++k) {
        int i = i0 + t + k * 512;
        d[k] = (i < e) ? dst[i] : -1;
        if (d[k] >= 0) atomicAdd(&cnt[d[k] >> 10], 1);
    }
    __syncthreads();
    if (t < MAX_BUCKETS) {
        gb[t] = cnt[t] ? bbase_s[t] + atomicAdd(&scur[t], cnt[t]) : 0;
        cur[t] = 0;
    }
    __syncthreads();
#pragma unroll
    for (int k = 0; k < 16; ++k) {
        int i = i0 + t + k * 512;
        if (d[k] >= 0) {
            int b = d[k] >> 10;
            int r = atomicAdd(&cur[b], 1);
            pairs[gb[b] + r] = make_uint2((unsigned)src[i], (unsigned)d[k]);
        }
    }
}

// ---------------------------------------------------------------------------
// build_k: one 1024-thread workgroup owns one bucket.
// ---------------------------------------------------------------------------
__global__ __launch_bounds__(1024) void build_k(const uint2* __restrict__ pairs,
                                                const int* __restrict__ bcnt,
                                                int n, int e,
                                                int* __restrict__ rp,
                                                float* __restrict__ dinv,
                                                int* __restrict__ col) {
    __shared__ int hist[1024];
    __shared__ int tsum[1024];
    __shared__ int sE[2];
    const int t = threadIdx.x;
    const int node0 = blockIdx.x << 10;
    if (t < MAX_BUCKETS) {
        int v = bcnt[t];
        int x = v;
#pragma unroll
        for (int off = 1; off < 64; off <<= 1) {
            int y = __shfl_up(x, off);
            if ((t & 63) >= off) x += y;
        }
        if (t == blockIdx.x) { sE[0] = x - v; sE[1] = x; }
    }
    hist[t] = 0;
    __syncthreads();
    const int ebase = sE[0];
    const int eend = sE[1];
    for (int i = ebase + t; i < eend; i += 1024) {
        uint2 p = pairs[i];
        atomicAdd(&hist[(int)p.y - node0], 1);
    }
    __syncthreads();
    const int deg = hist[t];
    tsum[t] = deg;
    __syncthreads();
    for (int off = 1; off < 1024; off <<= 1) {
        int x = (t >= off) ? tsum[t - off] : 0;
        __syncthreads();
        tsum[t] += x;
        __syncthreads();
    }
    const int excl = tsum[t] - deg;
    if (node0 + t < n) {
        rp[node0 + t] = ebase + excl;
        dinv[node0 + t] = rsqrtf((float)(deg + 1));
    }
    hist[t] = excl;                       // local fill cursor
    __syncthreads();
    for (int i = ebase + t; i < eend; i += 1024) {
        uint2 p = pairs[i];
        int r = atomicAdd(&hist[(int)p.y - node0], 1);
        col[ebase + r] = (int)p.x;
    }
    if (blockIdx.x == 0 && t == 0) rp[n] = e;
}

// ---------------------------------------------------------------------------
// MFMA GEMM: G[r][c] = bf16( dinv[r] * sum_k A[r][k]*Wt[c][k] ), K=128.
// ---------------------------------------------------------------------------
template <int OUT, bool F32IN>
__global__ __launch_bounds__(256) void mfma_gemm_k(
    const void* __restrict__ Av,             // [n][128] bf16 or f32
    const unsigned short* __restrict__ Wt,   // [OUT][128] bf16
    const float* __restrict__ dinv,
    unsigned short* __restrict__ G,          // [n][OUT] bf16
    int n) {
    constexpr int NF = OUT / 16;             // col fragments per wave
    __shared__ unsigned short lds[(128 + OUT) * 128];
    unsigned short* As = lds;                // 128 rows x 256B (swizzled)
    unsigned short* Ws = lds + 128 * 128;    // OUT rows x 256B (swizzled)

    const int tid = threadIdx.x;
    const int row0 = blockIdx.x * 128;

#pragma unroll
    for (int p = 0; p < 8; ++p) {
        int id = p * 256 + tid;
        int r = id >> 4, c = id & 15;
        uint4 v = make_uint4(0, 0, 0, 0);
        if (row0 + r < n) {
            if (F32IN) {
                const float* Af = (const float*)Av;
                const float4* fp =
                    (const float4*)&Af[(size_t)(row0 + r) * 128 + c * 8];
                float4 v0 = fp[0], v1 = fp[1];
                v.x = bf16_rn(v0.x) | (bf16_rn(v0.y) << 16);
                v.y = bf16_rn(v0.z) | (bf16_rn(v0.w) << 16);
                v.z = bf16_rn(v1.x) | (bf16_rn(v1.y) << 16);
                v.w = bf16_rn(v1.z) | (bf16_rn(v1.w) << 16);
            } else {
                const unsigned short* Ab = (const unsigned short*)Av;
                v = *(const uint4*)&Ab[(size_t)(row0 + r) * 128 + c * 8];
            }
        }
        int bo = r * 256 + ((c * 16) ^ ((r & 7) << 4));
        *(uint4*)((char*)As + bo) = v;
    }
#pragma unroll
    for (int p = 0; p < OUT / 16; ++p) {
        int id = p * 256 + tid;
        int r = id >> 4, c = id & 15;
        uint4 v = *(const uint4*)&Wt[(size_t)r * 128 + c * 8];
        int bo = r * 256 + ((c * 16) ^ ((r & 7) << 4));
        *(uint4*)((char*)Ws + bo) = v;
    }
    __syncthreads();

    const int wid = tid >> 6, lane = tid & 63;
    const int lq = lane >> 4, lr = lane & 15;
    const int woff = wid * 32;

    f32x4 acc[2][NF] = {};
#pragma unroll
    for (int ks = 0; ks < 4; ++ks) {
        short8 a[2];
#pragma unroll
        for (int m = 0; m < 2; ++m) {
            int r = woff + m * 16 + lr;
            int bo = r * 256 + ((lq * 16 + ks * 64) ^ ((r & 7) << 4));
            a[m] = *(const short8*)((const char*)As + bo);
        }
#pragma unroll
        for (int nf = 0; nf < NF; ++nf) {
            int c = nf * 16 + lr;
            int bo = c * 256 + ((lq * 16 + ks * 64) ^ ((c & 7) << 4));
            short8 b = *(const short8*)((const char*)Ws + bo);
            acc[0][nf] = __builtin_amdgcn_mfma_f32_16x16x32_bf16(a[0], b, acc[0][nf], 0, 0, 0);
            acc[1][nf] = __builtin_amdgcn_mfma_f32_16x16x32_bf16(a[1], b, acc[1][nf], 0, 0, 0);
        }
    }

#pragma unroll
    for (int m = 0; m < 2; ++m) {
#pragma unroll
        for (int j = 0; j < 4; ++j) {
            int r = row0 + woff + m * 16 + lq * 4 + j;
            if (r < n) {
                float d = dinv[r];
#pragma unroll
                for (int nf = 0; nf < NF; ++nf)
                    G[(size_t)r * OUT + nf * 16 + lr] =
                        (unsigned short)bf16_rn(d * acc[m][nf][j]);
            }
        }
    }
}

// ---------------------------------------------------------------------------
// Aggregation, hidden layers (OUT=128): 16-lane group per node (4 nodes per
// wave), lane slice = uint4 (8 bf16 cols).  8-deep exact batches + one
// clamped tail batch.  f32 accumulate, swish, bf16 packed H out.
// ---------------------------------------------------------------------------
__device__ inline void acc8(float* a, uint4 u) {
    a[0] += bf_lo(u.x); a[1] += bf_hi(u.x);
    a[2] += bf_lo(u.y); a[3] += bf_hi(u.y);
    a[4] += bf_lo(u.z); a[5] += bf_hi(u.z);
    a[6] += bf_lo(u.w); a[7] += bf_hi(u.w);
}

__global__ __launch_bounds__(512, 8) void agg_swish_k(const uint4* __restrict__ G4,
                                                      const int* __restrict__ rp,
                                                      const int* __restrict__ col,
                                                      const float* __restrict__ dinv,
                                                      const float* __restrict__ bias,
                                                      uint4* __restrict__ Hb4, int n) {
    const int i = (blockIdx.x * blockDim.x + threadIdx.x) >> 4;   // node
    const int sl = threadIdx.x & 15;                              // 16B slice
    if (i >= n) return;

    float a[8] = {0.f, 0.f, 0.f, 0.f, 0.f, 0.f, 0.f, 0.f};
    acc8(a, G4[(size_t)i * 16 + sl]);            // self-loop
    const int s = rp[i], e = rp[i + 1];
    int p = s;
    for (; p + 8 <= e; p += 8) {
        uint4 v[8];
#pragma unroll
        for (int k = 0; k < 8; ++k) {
            int j = col[p + k];
            v[k] = G4[(size_t)j * 16 + sl];
        }
#pragma unroll
        for (int k = 0; k < 8; ++k) acc8(a, v[k]);
    }
    if (p < e) {                                  // one clamped tail batch
        const int m = e - p;                      // 1..7
        uint4 v[8];
#pragma unroll
        for (int k = 0; k < 8; ++k) {
            int j = col[min(p + k, e - 1)];
            v[k] = G4[(size_t)j * 16 + sl];
        }
#pragma unroll
        for (int k = 0; k < 8; ++k)
            if (k < m) acc8(a, v[k]);
    }

    const float d = dinv[i];
    const float4 bl = *(const float4*)&bias[sl * 8];
    const float4 bh = *(const float4*)&bias[sl * 8 + 4];
    float r[8];
    r[0] = d * a[0] + bl.x; r[1] = d * a[1] + bl.y;
    r[2] = d * a[2] + bl.z; r[3] = d * a[3] + bl.w;
    r[4] = d * a[4] + bh.x; r[5] = d * a[5] + bh.y;
    r[6] = d * a[6] + bh.z; r[7] = d * a[7] + bh.w;
#pragma unroll
    for (int k = 0; k < 8; ++k) r[k] = r[k] / (1.f + expf(-r[k]));   // swish
    uint4 o;
    o.x = bf16_rn(r[0]) | (bf16_rn(r[1]) << 16);
    o.y = bf16_rn(r[2]) | (bf16_rn(r[3]) << 16);
    o.z = bf16_rn(r[4]) | (bf16_rn(r[5]) << 16);
    o.w = bf16_rn(r[6]) | (bf16_rn(r[7]) << 16);
    Hb4[(size_t)i * 16 + sl] = o;
}

// ---------------------------------------------------------------------------
// Final aggregation (OUT=64) + log_softmax: 16-lane group per node, lane
// slice = uint2 (4 bf16 classes).  Group-local shuffle reduction (xor<16).
// ---------------------------------------------------------------------------
__global__ __launch_bounds__(512, 8) void agg_lsm_k(const uint2* __restrict__ G2,
                                                    const int* __restrict__ rp,
                                                    const int* __restrict__ col,
                                                    const float* __restrict__ dinv,
                                                    const float* __restrict__ bias,
                                                    float* __restrict__ out, int n) {
    const int i = (blockIdx.x * blockDim.x + threadIdx.x) >> 4;   // node
    const int sl = threadIdx.x & 15;                              // 8B slice
    if (i >= n) return;

    float a[4] = {0.f, 0.f, 0.f, 0.f};
    {
        uint2 u = G2[(size_t)i * 16 + sl];
        a[0] += bf_lo(u.x); a[1] += bf_hi(u.x);
        a[2] += bf_lo(u.y); a[3] += bf_hi(u.y);
    }
    const int s = rp[i], e = rp[i + 1];
    int p = s;
    for (; p + 8 <= e; p += 8) {
        uint2 v[8];
#pragma unroll
        for (int k = 0; k < 8; ++k) {
            int j = col[p + k];
            v[k] = G2[(size_t)j * 16 + sl];
        }
#pragma unroll
        for (int k = 0; k < 8; ++k) {
            a[0] += bf_lo(v[k].x); a[1] += bf_hi(v[k].x);
            a[2] += bf_lo(v[k].y); a[3] += bf_hi(v[k].y);
        }
    }
    if (p < e) {
        const int m = e - p;
        uint2 v[8];
#pragma unroll
        for (int k = 0; k < 8; ++k) {
            int j = col[min(p + k, e - 1)];
            v[k] = G2[(size_t)j * 16 + sl];
        }
#pragma unroll
        for (int k = 0; k < 8; ++k)
            if (k < m) {
                a[0] += bf_lo(v[k].x); a[1] += bf_hi(v[k].x);
                a[2] += bf_lo(v[k].y); a[3] += bf_hi(v[k].y);
            }
    }

    const float d = dinv[i];
    const float4 bv = *(const float4*)&bias[sl * 4];
    float lg[4];
    lg[0] = d * a[0] + bv.x; lg[1] = d * a[1] + bv.y;
    lg[2] = d * a[2] + bv.z; lg[3] = d * a[3] + bv.w;

    float m0 = fmaxf(fmaxf(lg[0], lg[1]), fmaxf(lg[2], lg[3]));
#pragma unroll
    for (int off = 1; off < 16; off <<= 1) m0 = fmaxf(m0, __shfl_xor(m0, off));
    float es = expf(lg[0] - m0) + expf(lg[1] - m0) +
               expf(lg[2] - m0) + expf(lg[3] - m0);
#pragma unroll
    for (int off = 1; off < 16; off <<= 1) es += __shfl_xor(es, off);
    const float lse = m0 + logf(es);
    float4 o;
    o.x = lg[0] - lse; o.y = lg[1] - lse; o.z = lg[2] - lse; o.w = lg[3] - lse;
    *(float4*)&out[(size_t)i * 64 + sl * 4] = o;
}

extern "C" void kernel_launch(void* const* d_in, const int* in_sizes, int n_in,
                              void* d_out, int out_size, void* d_ws, size_t ws_size,
                              hipStream_t stream) {
    const float* x = (const float*)d_in[0];
    const int* ei = (const int*)d_in[1];
    const float* W0 = (const float*)d_in[2];
    const float* b0 = (const float*)d_in[3];
    const float* W1 = (const float*)d_in[4];
    const float* b1 = (const float*)d_in[5];
    const float* W2 = (const float*)d_in[6];
    const float* b2 = (const float*)d_in[7];
    float* out = (float*)d_out;

    const int n = in_sizes[0] / 128;
    const int e = in_sizes[1] / 2;
    const int* src = ei;
    const int* dst = ei + e;

    char* ws = (char*)d_ws;
    size_t off = 0;
    auto alloc = [&](size_t bytes) -> void* {
        void* p = ws + off;
        off += (bytes + 255) & ~(size_t)255;
        return p;
    };
    int* bcnt = (int*)alloc(MAX_BUCKETS * 4 * 2);  // bcnt[64] | scur[64]
    int* scur = bcnt + MAX_BUCKETS;
    int* rp = (int*)alloc((size_t)(n + 1) * 4);    // CSR row_ptr
    float* dinv = (float*)alloc((size_t)n * 4);
    int* col = (int*)alloc((size_t)e * 4);         // CSR col (src per dst)
    uint2* pairs = (uint2*)alloc((size_t)e * 8);   // bucketed (src,dst)
    unsigned short* wt = (unsigned short*)alloc(40960 * 2);  // w0t|w1t|w2t
    unsigned short* g = (unsigned short*)alloc((size_t)n * 256);   // bf16 pre-agg
    unsigned short* hb = (unsigned short*)alloc((size_t)n * 256);  // bf16 post-act

    unsigned short* w0t = wt;
    unsigned short* w1t = wt + 16384;
    unsigned short* w2t = wt + 32768;

    hipMemsetAsync(bcnt, 0, MAX_BUCKETS * 4 * 2, stream);
    prep_k<<<CVT_BLOCKS + (e + 4095) / 4096, 256, 0, stream>>>(dst, e, bcnt,
                                                               W0, W1, W2, wt);
    scatter_k<<<(e + 8191) / 8192, 512, 0, stream>>>(src, dst, e, bcnt, scur, pairs);
    const int nbuck = (n + NODES_PER_BUCKET - 1) / NODES_PER_BUCKET;  // 49
    build_k<<<nbuck, 1024, 0, stream>>>(pairs, bcnt, n, e, rp, dinv, col);

    const int gb = (n + 127) / 128;
    const int ab = (n + 31) / 32;                  // 32 nodes per 512-thr block

    mfma_gemm_k<128, true><<<gb, 256, 0, stream>>>(x, w0t, dinv, g, n);
    agg_swish_k<<<ab, 512, 0, stream>>>((const uint4*)g, rp, col, dinv, b0,
                                        (uint4*)hb, n);
    mfma_gemm_k<128, false><<<gb, 256, 0, stream>>>(hb, w1t, dinv, g, n);
    agg_swish_k<<<ab, 512, 0, stream>>>((const uint4*)g, rp, col, dinv, b1,
                                        (uint4*)hb, n);
    mfma_gemm_k<64, false><<<gb, 256, 0, stream>>>(hb, w2t, dinv, g, n);
    agg_lsm_k<<<ab, 512, 0, stream>>>((const uint2*)g, rp, col, dinv, b2, out, n);
}

// Round 9
// 172.358 us; speedup vs baseline: 1.3757x; 1.3757x over previous
//
#include <hip/hip_runtime.h>

// ---------------------------------------------------------------------------
// GCN: 3-layer, N=50000 nodes, E=800000 edges, F_IN=128, H=128, C=64.
//   norm[e] = dinv[src]*dinv[dst]  =>  fold dinv into GEMM epilogue and
//   aggregation epilogue.  Self-loop = + g[i].
//   layer: g = dinv .* (A @ W);  h = act(dinv[i]*(g[i] + sum_{j->i} g[j]) + b)
// R2: hierarchical scan. R3: G bf16. R4: bucketed counting-sort graph build.
// R5: MFMA GEMMs (16x16x32 bf16), bf16 feature path, XOR-swizzled LDS.
// R6: 8-deep gather unroll. R7: 16-deep predicated (REGRESSED: VALU+waste).
// R8: 16-lane groups, 4 nodes/wave, 8-deep = 32 streams/wave (REGRESSED:
//     launch_bounds(512,8) capped VGPR at 64 -> uint4 v[8] spilled to
//     scratch; VGPR=32, WRITE_SIZE 111MB on a 12.8MB output).
// R9: same structure, launch_bounds(512,4) (<=128 VGPR) -> no spill.
// ---------------------------------------------------------------------------

#define NODES_PER_BUCKET 1024      // bucket = dst >> 10
#define MAX_BUCKETS 64             // n <= 64K nodes (50000 -> 49 buckets)
#define CVT_BLOCKS 160             // 40960 weight elems / 256

typedef __attribute__((ext_vector_type(8))) short short8;
typedef __attribute__((ext_vector_type(4))) float f32x4;

__device__ inline unsigned bf16_rn(float x) {          // rne, no NaN expected
    unsigned u = __float_as_uint(x);
    return (u + 0x7fffu + ((u >> 16) & 1u)) >> 16;
}
__device__ inline float bf_lo(unsigned u) { return __uint_as_float(u << 16); }
__device__ inline float bf_hi(unsigned u) { return __uint_as_float(u & 0xffff0000u); }

// ---------------------------------------------------------------------------
// prep_k: blocks [0,CVT_BLOCKS) convert W0|W1|W2 f32 -> bf16 Wt[out][128];
//         remaining blocks build the 64-bucket dst histogram.
// ---------------------------------------------------------------------------
__global__ __launch_bounds__(256) void prep_k(const int* __restrict__ dst, int e,
                                              int* __restrict__ bcnt,
                                              const float* __restrict__ W0,
                                              const float* __restrict__ W1,
                                              const float* __restrict__ W2,
                                              unsigned short* __restrict__ Wt) {
    const int t = threadIdx.x;
    if (blockIdx.x < CVT_BLOCKS) {
        int id = blockIdx.x * 256 + t;              // 0 .. 40959
        const float* W;
        int out, loc;
        if (id < 16384)      { W = W0; out = 128; loc = id; }
        else if (id < 32768) { W = W1; out = 128; loc = id - 16384; }
        else                 { W = W2; out = 64;  loc = id - 32768; }
        int o = loc >> 7, k = loc & 127;
        Wt[id] = (unsigned short)bf16_rn(W[k * out + o]);
        return;
    }
    __shared__ int h[MAX_BUCKETS];
    if (t < MAX_BUCKETS) h[t] = 0;
    __syncthreads();
    const int i0 = (blockIdx.x - CVT_BLOCKS) * 4096;
#pragma unroll
    for (int k = 0; k < 16; ++k) {
        int i = i0 + t + k * 256;
        if (i < e) atomicAdd(&h[dst[i] >> 10], 1);
    }
    __syncthreads();
    if (t < MAX_BUCKETS && h[t]) atomicAdd(&bcnt[t], h[t]);
}

// ---------------------------------------------------------------------------
// scatter_k: block-chunked pair scatter into bucket segments.
// ---------------------------------------------------------------------------
__global__ __launch_bounds__(512) void scatter_k(const int* __restrict__ src,
                                                 const int* __restrict__ dst,
                                                 int e,
                                                 const int* __restrict__ bcnt,
                                                 int* __restrict__ scur,
                                                 uint2* __restrict__ pairs) {
    __shared__ int bbase_s[MAX_BUCKETS];
    __shared__ int cnt[MAX_BUCKETS];
    __shared__ int cur[MAX_BUCKETS];
    __shared__ int gb[MAX_BUCKETS];
    const int t = threadIdx.x;
    if (t < MAX_BUCKETS) {
        int v = bcnt[t];                        // zeros beyond nbuck
        int x = v;
#pragma unroll
        for (int off = 1; off < 64; off <<= 1) {
            int y = __shfl_up(x, off);
            if ((t & 63) >= off) x += y;
        }
        bbase_s[t] = x - v;                     // exclusive scan
        cnt[t] = 0;
    }
    __syncthreads();
    const int i0 = blockIdx.x * 8192;
    int d[16];
#pragma unroll
    for (int k = 0; k < 16; ++k) {
        int i = i0 + t + k * 512;
        d[k] = (i < e) ? dst[i] : -1;
        if (d[k] >= 0) atomicAdd(&cnt[d[k] >> 10], 1);
    }
    __syncthreads();
    if (t < MAX_BUCKETS) {
        gb[t] = cnt[t] ? bbase_s[t] + atomicAdd(&scur[t], cnt[t]) : 0;
        cur[t] = 0;
    }
    __syncthreads();
#pragma unroll
    for (int k = 0; k < 16; ++k) {
        int i = i0 + t + k * 512;
        if (d[k] >= 0) {
            int b = d[k] >> 10;
            int r = atomicAdd(&cur[b], 1);
            pairs[gb[b] + r] = make_uint2((unsigned)src[i], (unsigned)d[k]);
        }
    }
}

// ---------------------------------------------------------------------------
// build_k: one 1024-thread workgroup owns one bucket.
// ---------------------------------------------------------------------------
__global__ __launch_bounds__(1024) void build_k(const uint2* __restrict__ pairs,
                                                const int* __restrict__ bcnt,
                                                int n, int e,
                                                int* __restrict__ rp,
                                                float* __restrict__ dinv,
                                                int* __restrict__ col) {
    __shared__ int hist[1024];
    __shared__ int tsum[1024];
    __shared__ int sE[2];
    const int t = threadIdx.x;
    const int node0 = blockIdx.x << 10;
    if (t < MAX_BUCKETS) {
        int v = bcnt[t];
        int x = v;
#pragma unroll
        for (int off = 1; off < 64; off <<= 1) {
            int y = __shfl_up(x, off);
            if ((t & 63) >= off) x += y;
        }
        if (t == blockIdx.x) { sE[0] = x - v; sE[1] = x; }
    }
    hist[t] = 0;
    __syncthreads();
    const int ebase = sE[0];
    const int eend = sE[1];
    for (int i = ebase + t; i < eend; i += 1024) {
        uint2 p = pairs[i];
        atomicAdd(&hist[(int)p.y - node0], 1);
    }
    __syncthreads();
    const int deg = hist[t];
    tsum[t] = deg;
    __syncthreads();
    for (int off = 1; off < 1024; off <<= 1) {
        int x = (t >= off) ? tsum[t - off] : 0;
        __syncthreads();
        tsum[t] += x;
        __syncthreads();
    }
    const int excl = tsum[t] - deg;
    if (node0 + t < n) {
        rp[node0 + t] = ebase + excl;
        dinv[node0 + t] = rsqrtf((float)(deg + 1));
    }
    hist[t] = excl;                       // local fill cursor
    __syncthreads();
    for (int i = ebase + t; i < eend; i += 1024) {
        uint2 p = pairs[i];
        int r = atomicAdd(&hist[(int)p.y - node0], 1);
        col[ebase + r] = (int)p.x;
    }
    if (blockIdx.x == 0 && t == 0) rp[n] = e;
}

// ---------------------------------------------------------------------------
// MFMA GEMM: G[r][c] = bf16( dinv[r] * sum_k A[r][k]*Wt[c][k] ), K=128.
// ---------------------------------------------------------------------------
template <int OUT, bool F32IN>
__global__ __launch_bounds__(256) void mfma_gemm_k(
    const void* __restrict__ Av,             // [n][128] bf16 or f32
    const unsigned short* __restrict__ Wt,   // [OUT][128] bf16
    const float* __restrict__ dinv,
    unsigned short* __restrict__ G,          // [n][OUT] bf16
    int n) {
    constexpr int NF = OUT / 16;             // col fragments per wave
    __shared__ unsigned short lds[(128 + OUT) * 128];
    unsigned short* As = lds;                // 128 rows x 256B (swizzled)
    unsigned short* Ws = lds + 128 * 128;    // OUT rows x 256B (swizzled)

    const int tid = threadIdx.x;
    const int row0 = blockIdx.x * 128;

#pragma unroll
    for (int p = 0; p < 8; ++p) {
        int id = p * 256 + tid;
        int r = id >> 4, c = id & 15;
        uint4 v = make_uint4(0, 0, 0, 0);
        if (row0 + r < n) {
            if (F32IN) {
                const float* Af = (const float*)Av;
                const float4* fp =
                    (const float4*)&Af[(size_t)(row0 + r) * 128 + c * 8];
                float4 v0 = fp[0], v1 = fp[1];
                v.x = bf16_rn(v0.x) | (bf16_rn(v0.y) << 16);
                v.y = bf16_rn(v0.z) | (bf16_rn(v0.w) << 16);
                v.z = bf16_rn(v1.x) | (bf16_rn(v1.y) << 16);
                v.w = bf16_rn(v1.z) | (bf16_rn(v1.w) << 16);
            } else {
                const unsigned short* Ab = (const unsigned short*)Av;
                v = *(const uint4*)&Ab[(size_t)(row0 + r) * 128 + c * 8];
            }
        }
        int bo = r * 256 + ((c * 16) ^ ((r & 7) << 4));
        *(uint4*)((char*)As + bo) = v;
    }
#pragma unroll
    for (int p = 0; p < OUT / 16; ++p) {
        int id = p * 256 + tid;
        int r = id >> 4, c = id & 15;
        uint4 v = *(const uint4*)&Wt[(size_t)r * 128 + c * 8];
        int bo = r * 256 + ((c * 16) ^ ((r & 7) << 4));
        *(uint4*)((char*)Ws + bo) = v;
    }
    __syncthreads();

    const int wid = tid >> 6, lane = tid & 63;
    const int lq = lane >> 4, lr = lane & 15;
    const int woff = wid * 32;

    f32x4 acc[2][NF] = {};
#pragma unroll
    for (int ks = 0; ks < 4; ++ks) {
        short8 a[2];
#pragma unroll
        for (int m = 0; m < 2; ++m) {
            int r = woff + m * 16 + lr;
            int bo = r * 256 + ((lq * 16 + ks * 64) ^ ((r & 7) << 4));
            a[m] = *(const short8*)((const char*)As + bo);
        }
#pragma unroll
        for (int nf = 0; nf < NF; ++nf) {
            int c = nf * 16 + lr;
            int bo = c * 256 + ((lq * 16 + ks * 64) ^ ((c & 7) << 4));
            short8 b = *(const short8*)((const char*)Ws + bo);
            acc[0][nf] = __builtin_amdgcn_mfma_f32_16x16x32_bf16(a[0], b, acc[0][nf], 0, 0, 0);
            acc[1][nf] = __builtin_amdgcn_mfma_f32_16x16x32_bf16(a[1], b, acc[1][nf], 0, 0, 0);
        }
    }

#pragma unroll
    for (int m = 0; m < 2; ++m) {
#pragma unroll
        for (int j = 0; j < 4; ++j) {
            int r = row0 + woff + m * 16 + lq * 4 + j;
            if (r < n) {
                float d = dinv[r];
#pragma unroll
                for (int nf = 0; nf < NF; ++nf)
                    G[(size_t)r * OUT + nf * 16 + lr] =
                        (unsigned short)bf16_rn(d * acc[m][nf][j]);
            }
        }
    }
}

// ---------------------------------------------------------------------------
// Aggregation, hidden layers (OUT=128): 16-lane group per node (4 nodes per
// wave), lane slice = uint4 (8 bf16 cols).  8-deep exact batches + one
// clamped tail batch.  f32 accumulate, swish, bf16 packed H out.
// launch_bounds(512,4): <=128 VGPR so the uint4 v[8] batch stays in regs.
// ---------------------------------------------------------------------------
__device__ inline void acc8(float* a, uint4 u) {
    a[0] += bf_lo(u.x); a[1] += bf_hi(u.x);
    a[2] += bf_lo(u.y); a[3] += bf_hi(u.y);
    a[4] += bf_lo(u.z); a[5] += bf_hi(u.z);
    a[6] += bf_lo(u.w); a[7] += bf_hi(u.w);
}

__global__ __launch_bounds__(512, 4) void agg_swish_k(const uint4* __restrict__ G4,
                                                      const int* __restrict__ rp,
                                                      const int* __restrict__ col,
                                                      const float* __restrict__ dinv,
                                                      const float* __restrict__ bias,
                                                      uint4* __restrict__ Hb4, int n) {
    const int i = (blockIdx.x * blockDim.x + threadIdx.x) >> 4;   // node
    const int sl = threadIdx.x & 15;                              // 16B slice
    if (i >= n) return;

    float a[8] = {0.f, 0.f, 0.f, 0.f, 0.f, 0.f, 0.f, 0.f};
    acc8(a, G4[(size_t)i * 16 + sl]);            // self-loop
    const int s = rp[i], e = rp[i + 1];
    int p = s;
    for (; p + 8 <= e; p += 8) {
        uint4 v[8];
#pragma unroll
        for (int k = 0; k < 8; ++k) {
            int j = col[p + k];
            v[k] = G4[(size_t)j * 16 + sl];
        }
#pragma unroll
        for (int k = 0; k < 8; ++k) acc8(a, v[k]);
    }
    if (p < e) {                                  // one clamped tail batch
        const int m = e - p;                      // 1..7
        uint4 v[8];
#pragma unroll
        for (int k = 0; k < 8; ++k) {
            int j = col[min(p + k, e - 1)];
            v[k] = G4[(size_t)j * 16 + sl];
        }
#pragma unroll
        for (int k = 0; k < 8; ++k)
            if (k < m) acc8(a, v[k]);
    }

    const float d = dinv[i];
    const float4 bl = *(const float4*)&bias[sl * 8];
    const float4 bh = *(const float4*)&bias[sl * 8 + 4];
    float r[8];
    r[0] = d * a[0] + bl.x; r[1] = d * a[1] + bl.y;
    r[2] = d * a[2] + bl.z; r[3] = d * a[3] + bl.w;
    r[4] = d * a[4] + bh.x; r[5] = d * a[5] + bh.y;
    r[6] = d * a[6] + bh.z; r[7] = d * a[7] + bh.w;
#pragma unroll
    for (int k = 0; k < 8; ++k) r[k] = r[k] / (1.f + expf(-r[k]));   // swish
    uint4 o;
    o.x = bf16_rn(r[0]) | (bf16_rn(r[1]) << 16);
    o.y = bf16_rn(r[2]) | (bf16_rn(r[3]) << 16);
    o.z = bf16_rn(r[4]) | (bf16_rn(r[5]) << 16);
    o.w = bf16_rn(r[6]) | (bf16_rn(r[7]) << 16);
    Hb4[(size_t)i * 16 + sl] = o;
}

// ---------------------------------------------------------------------------
// Final aggregation (OUT=64) + log_softmax: 16-lane group per node, lane
// slice = uint2 (4 bf16 classes).  Group-local shuffle reduction (xor<16).
// ---------------------------------------------------------------------------
__global__ __launch_bounds__(512, 4) void agg_lsm_k(const uint2* __restrict__ G2,
                                                    const int* __restrict__ rp,
                                                    const int* __restrict__ col,
                                                    const float* __restrict__ dinv,
                                                    const float* __restrict__ bias,
                                                    float* __restrict__ out, int n) {
    const int i = (blockIdx.x * blockDim.x + threadIdx.x) >> 4;   // node
    const int sl = threadIdx.x & 15;                              // 8B slice
    if (i >= n) return;

    float a[4] = {0.f, 0.f, 0.f, 0.f};
    {
        uint2 u = G2[(size_t)i * 16 + sl];
        a[0] += bf_lo(u.x); a[1] += bf_hi(u.x);
        a[2] += bf_lo(u.y); a[3] += bf_hi(u.y);
    }
    const int s = rp[i], e = rp[i + 1];
    int p = s;
    for (; p + 8 <= e; p += 8) {
        uint2 v[8];
#pragma unroll
        for (int k = 0; k < 8; ++k) {
            int j = col[p + k];
            v[k] = G2[(size_t)j * 16 + sl];
        }
#pragma unroll
        for (int k = 0; k < 8; ++k) {
            a[0] += bf_lo(v[k].x); a[1] += bf_hi(v[k].x);
            a[2] += bf_lo(v[k].y); a[3] += bf_hi(v[k].y);
        }
    }
    if (p < e) {
        const int m = e - p;
        uint2 v[8];
#pragma unroll
        for (int k = 0; k < 8; ++k) {
            int j = col[min(p + k, e - 1)];
            v[k] = G2[(size_t)j * 16 + sl];
        }
#pragma unroll
        for (int k = 0; k < 8; ++k)
            if (k < m) {
                a[0] += bf_lo(v[k].x); a[1] += bf_hi(v[k].x);
                a[2] += bf_lo(v[k].y); a[3] += bf_hi(v[k].y);
            }
    }

    const float d = dinv[i];
    const float4 bv = *(const float4*)&bias[sl * 4];
    float lg[4];
    lg[0] = d * a[0] + bv.x; lg[1] = d * a[1] + bv.y;
    lg[2] = d * a[2] + bv.z; lg[3] = d * a[3] + bv.w;

    float m0 = fmaxf(fmaxf(lg[0], lg[1]), fmaxf(lg[2], lg[3]));
#pragma unroll
    for (int off = 1; off < 16; off <<= 1) m0 = fmaxf(m0, __shfl_xor(m0, off));
    float es = expf(lg[0] - m0) + expf(lg[1] - m0) +
               expf(lg[2] - m0) + expf(lg[3] - m0);
#pragma unroll
    for (int off = 1; off < 16; off <<= 1) es += __shfl_xor(es, off);
    const float lse = m0 + logf(es);
    float4 o;
    o.x = lg[0] - lse; o.y = lg[1] - lse; o.z = lg[2] - lse; o.w = lg[3] - lse;
    *(float4*)&out[(size_t)i * 64 + sl * 4] = o;
}

extern "C" void kernel_launch(void* const* d_in, const int* in_sizes, int n_in,
                              void* d_out, int out_size, void* d_ws, size_t ws_size,
                              hipStream_t stream) {
    const float* x = (const float*)d_in[0];
    const int* ei = (const int*)d_in[1];
    const float* W0 = (const float*)d_in[2];
    const float* b0 = (const float*)d_in[3];
    const float* W1 = (const float*)d_in[4];
    const float* b1 = (const float*)d_in[5];
    const float* W2 = (const float*)d_in[6];
    const float* b2 = (const float*)d_in[7];
    float* out = (float*)d_out;

    const int n = in_sizes[0] / 128;
    const int e = in_sizes[1] / 2;
    const int* src = ei;
    const int* dst = ei + e;

    char* ws = (char*)d_ws;
    size_t off = 0;
    auto alloc = [&](size_t bytes) -> void* {
        void* p = ws + off;
        off += (bytes + 255) & ~(size_t)255;
        return p;
    };
    int* bcnt = (int*)alloc(MAX_BUCKETS * 4 * 2);  // bcnt[64] | scur[64]
    int* scur = bcnt + MAX_BUCKETS;
    int* rp = (int*)alloc((size_t)(n + 1) * 4);    // CSR row_ptr
    float* dinv = (float*)alloc((size_t)n * 4);
    int* col = (int*)alloc((size_t)e * 4);         // CSR col (src per dst)
    uint2* pairs = (uint2*)alloc((size_t)e * 8);   // bucketed (src,dst)
    unsigned short* wt = (unsigned short*)alloc(40960 * 2);  // w0t|w1t|w2t
    unsigned short* g = (unsigned short*)alloc((size_t)n * 256);   // bf16 pre-agg
    unsigned short* hb = (unsigned short*)alloc((size_t)n * 256);  // bf16 post-act

    unsigned short* w0t = wt;
    unsigned short* w1t = wt + 16384;
    unsigned short* w2t = wt + 32768;

    hipMemsetAsync(bcnt, 0, MAX_BUCKETS * 4 * 2, stream);
    prep_k<<<CVT_BLOCKS + (e + 4095) / 4096, 256, 0, stream>>>(dst, e, bcnt,
                                                               W0, W1, W2, wt);
    scatter_k<<<(e + 8191) / 8192, 512, 0, stream>>>(src, dst, e, bcnt, scur, pairs);
    const int nbuck = (n + NODES_PER_BUCKET - 1) / NODES_PER_BUCKET;  // 49
    build_k<<<nbuck, 1024, 0, stream>>>(pairs, bcnt, n, e, rp, dinv, col);

    const int gb = (n + 127) / 128;
    const int ab = (n + 31) / 32;                  // 32 nodes per 512-thr block

    mfma_gemm_k<128, true><<<gb, 256, 0, stream>>>(x, w0t, dinv, g, n);
    agg_swish_k<<<ab, 512, 0, stream>>>((const uint4*)g, rp, col, dinv, b0,
                                        (uint4*)hb, n);
    mfma_gemm_k<128, false><<<gb, 256, 0, stream>>>(hb, w1t, dinv, g, n);
    agg_swish_k<<<ab, 512, 0, stream>>>((const uint4*)g, rp, col, dinv, b1,
                                        (uint4*)hb, n);
    mfma_gemm_k<64, false><<<gb, 256, 0, stream>>>(hb, w2t, dinv, g, n);
    agg_lsm_k<<<ab, 512, 0, stream>>>((const uint2*)g, rp, col, dinv, b2, out, n);
}

// Round 10
// 162.463 us; speedup vs baseline: 1.4595x; 1.0609x over previous
//
#include <hip/hip_runtime.h>

// ---------------------------------------------------------------------------
// GCN: 3-layer, N=50000 nodes, E=800000 edges, F_IN=128, H=128, C=64.
//   norm[e] = dinv[src]*dinv[dst]  =>  fold dinv into GEMM epilogue and
//   aggregation epilogue.  Self-loop = + g[i].
//   g0 = dinv.*(x@W0); h = swish(dinv[i]*(g[i]+sum g[j]) + b); ...
// R2: hierarchical scan. R3: G bf16. R4: bucketed counting-sort graph build.
// R5: MFMA GEMMs, bf16 feature path, XOR-swizzled LDS.
// R8/R9: agg = 16-lane groups, 4 nodes/wave, 8-deep batches (32 streams/wave);
//        launch_bounds min-waves=4 (NOT 8: 64-VGPR cap spilled the batch).
// R10: agg_swish fused into the following GEMM (gather -> swish -> LDS A-tile
//      -> MFMA) -> h never hits global (saves 2x25.6MB + 2 dispatches);
//      pairs packed to 4B (src<<10|ldst, n<2^16).
// ---------------------------------------------------------------------------

#define NODES_PER_BUCKET 1024      // bucket = dst >> 10
#define MAX_BUCKETS 64             // n <= 64K nodes (50000 -> 49 buckets)
#define CVT_BLOCKS 160             // 40960 weight elems / 256

typedef __attribute__((ext_vector_type(8))) short short8;
typedef __attribute__((ext_vector_type(4))) float f32x4;

__device__ inline unsigned bf16_rn(float x) {          // rne, no NaN expected
    unsigned u = __float_as_uint(x);
    return (u + 0x7fffu + ((u >> 16) & 1u)) >> 16;
}
__device__ inline float bf_lo(unsigned u) { return __uint_as_float(u << 16); }
__device__ inline float bf_hi(unsigned u) { return __uint_as_float(u & 0xffff0000u); }

// ---------------------------------------------------------------------------
// prep_k: blocks [0,CVT_BLOCKS) convert W0|W1|W2 f32 -> bf16 Wt[out][128];
//         remaining blocks build the 64-bucket dst histogram.
// ---------------------------------------------------------------------------
__global__ __launch_bounds__(256) void prep_k(const int* __restrict__ dst, int e,
                                              int* __restrict__ bcnt,
                                              const float* __restrict__ W0,
                                              const float* __restrict__ W1,
                                              const float* __restrict__ W2,
                                              unsigned short* __restrict__ Wt) {
    const int t = threadIdx.x;
    if (blockIdx.x < CVT_BLOCKS) {
        int id = blockIdx.x * 256 + t;              // 0 .. 40959
        const float* W;
        int out, loc;
        if (id < 16384)      { W = W0; out = 128; loc = id; }
        else if (id < 32768) { W = W1; out = 128; loc = id - 16384; }
        else                 { W = W2; out = 64;  loc = id - 32768; }
        int o = loc >> 7, k = loc & 127;
        Wt[id] = (unsigned short)bf16_rn(W[k * out + o]);
        return;
    }
    __shared__ int h[MAX_BUCKETS];
    if (t < MAX_BUCKETS) h[t] = 0;
    __syncthreads();
    const int i0 = (blockIdx.x - CVT_BLOCKS) * 4096;
#pragma unroll
    for (int k = 0; k < 16; ++k) {
        int i = i0 + t + k * 256;
        if (i < e) atomicAdd(&h[dst[i] >> 10], 1);
    }
    __syncthreads();
    if (t < MAX_BUCKETS && h[t]) atomicAdd(&bcnt[t], h[t]);
}

// ---------------------------------------------------------------------------
// scatter_k: block-chunked packed-pair scatter into bucket segments.
// pair = (src << 10) | (dst & 1023)   [n < 2^16 so src fits 16 bits]
// ---------------------------------------------------------------------------
__global__ __launch_bounds__(512) void scatter_k(const int* __restrict__ src,
                                                 const int* __restrict__ dst,
                                                 int e,
                                                 const int* __restrict__ bcnt,
                                                 int* __restrict__ scur,
                                                 unsigned* __restrict__ pairs) {
    __shared__ int bbase_s[MAX_BUCKETS];
    __shared__ int cnt[MAX_BUCKETS];
    __shared__ int cur[MAX_BUCKETS];
    __shared__ int gb[MAX_BUCKETS];
    const int t = threadIdx.x;
    if (t < MAX_BUCKETS) {
        int v = bcnt[t];                        // zeros beyond nbuck
        int x = v;
#pragma unroll
        for (int off = 1; off < 64; off <<= 1) {
            int y = __shfl_up(x, off);
            if ((t & 63) >= off) x += y;
        }
        bbase_s[t] = x - v;                     // exclusive scan
        cnt[t] = 0;
    }
    __syncthreads();
    const int i0 = blockIdx.x * 8192;
    int d[16];
#pragma unroll
    for (int k = 0; k < 16; ++k) {
        int i = i0 + t + k * 512;
        d[k] = (i < e) ? dst[i] : -1;
        if (d[k] >= 0) atomicAdd(&cnt[d[k] >> 10], 1);
    }
    __syncthreads();
    if (t < MAX_BUCKETS) {
        gb[t] = cnt[t] ? bbase_s[t] + atomicAdd(&scur[t], cnt[t]) : 0;
        cur[t] = 0;
    }
    __syncthreads();
#pragma unroll
    for (int k = 0; k < 16; ++k) {
        int i = i0 + t + k * 512;
        if (d[k] >= 0) {
            int b = d[k] >> 10;
            int r = atomicAdd(&cur[b], 1);
            pairs[gb[b] + r] = ((unsigned)src[i] << 10) | ((unsigned)d[k] & 1023u);
        }
    }
}

// ---------------------------------------------------------------------------
// build_k: one 1024-thread workgroup owns one bucket.
// ---------------------------------------------------------------------------
__global__ __launch_bounds__(1024) void build_k(const unsigned* __restrict__ pairs,
                                                const int* __restrict__ bcnt,
                                                int n, int e,
                                                int* __restrict__ rp,
                                                float* __restrict__ dinv,
                                                int* __restrict__ col) {
    __shared__ int hist[1024];
    __shared__ int tsum[1024];
    __shared__ int sE[2];
    const int t = threadIdx.x;
    if (t < MAX_BUCKETS) {
        int v = bcnt[t];
        int x = v;
#pragma unroll
        for (int off = 1; off < 64; off <<= 1) {
            int y = __shfl_up(x, off);
            if ((t & 63) >= off) x += y;
        }
        if (t == blockIdx.x) { sE[0] = x - v; sE[1] = x; }
    }
    hist[t] = 0;
    __syncthreads();
    const int ebase = sE[0];
    const int eend = sE[1];
    for (int i = ebase + t; i < eend; i += 1024)
        atomicAdd(&hist[pairs[i] & 1023u], 1);
    __syncthreads();
    const int deg = hist[t];
    tsum[t] = deg;
    __syncthreads();
    for (int off = 1; off < 1024; off <<= 1) {
        int x = (t >= off) ? tsum[t - off] : 0;
        __syncthreads();
        tsum[t] += x;
        __syncthreads();
    }
    const int excl = tsum[t] - deg;
    const int node0 = blockIdx.x << 10;
    if (node0 + t < n) {
        rp[node0 + t] = ebase + excl;
        dinv[node0 + t] = rsqrtf((float)(deg + 1));
    }
    hist[t] = excl;                       // local fill cursor
    __syncthreads();
    for (int i = ebase + t; i < eend; i += 1024) {
        unsigned p = pairs[i];
        int r = atomicAdd(&hist[p & 1023u], 1);
        col[ebase + r] = (int)(p >> 10);
    }
    if (blockIdx.x == 0 && t == 0) rp[n] = e;
}

// ---------------------------------------------------------------------------
// MFMA GEMM (layer 0): G[r][c] = bf16( dinv[r]*sum_k x[r][k]*Wt[c][k] ), K=128.
// f32 input converted to bf16 during LDS staging.
// ---------------------------------------------------------------------------
__global__ __launch_bounds__(256) void mfma_gemm0_k(
    const float* __restrict__ Af,            // [n][128] f32
    const unsigned short* __restrict__ Wt,   // [128][128] bf16
    const float* __restrict__ dinv,
    unsigned short* __restrict__ G,          // [n][128] bf16
    int n) {
    __shared__ unsigned short lds[256 * 128];
    unsigned short* As = lds;                // 128 rows x 256B (swizzled)
    unsigned short* Ws = lds + 128 * 128;

    const int tid = threadIdx.x;
    const int row0 = blockIdx.x * 128;

#pragma unroll
    for (int p = 0; p < 8; ++p) {
        int id = p * 256 + tid;
        int r = id >> 4, c = id & 15;
        uint4 v = make_uint4(0, 0, 0, 0);
        if (row0 + r < n) {
            const float4* fp = (const float4*)&Af[(size_t)(row0 + r) * 128 + c * 8];
            float4 v0 = fp[0], v1 = fp[1];
            v.x = bf16_rn(v0.x) | (bf16_rn(v0.y) << 16);
            v.y = bf16_rn(v0.z) | (bf16_rn(v0.w) << 16);
            v.z = bf16_rn(v1.x) | (bf16_rn(v1.y) << 16);
            v.w = bf16_rn(v1.z) | (bf16_rn(v1.w) << 16);
        }
        int bo = r * 256 + ((c * 16) ^ ((r & 7) << 4));
        *(uint4*)((char*)As + bo) = v;
    }
#pragma unroll
    for (int p = 0; p < 8; ++p) {
        int id = p * 256 + tid;
        int r = id >> 4, c = id & 15;
        uint4 v = *(const uint4*)&Wt[(size_t)r * 128 + c * 8];
        int bo = r * 256 + ((c * 16) ^ ((r & 7) << 4));
        *(uint4*)((char*)Ws + bo) = v;
    }
    __syncthreads();

    const int wid = tid >> 6, lane = tid & 63;
    const int lq = lane >> 4, lr = lane & 15;
    const int woff = wid * 32;

    f32x4 acc[2][8] = {};
#pragma unroll
    for (int ks = 0; ks < 4; ++ks) {
        short8 a[2];
#pragma unroll
        for (int m = 0; m < 2; ++m) {
            int r = woff + m * 16 + lr;
            int bo = r * 256 + ((lq * 16 + ks * 64) ^ ((r & 7) << 4));
            a[m] = *(const short8*)((const char*)As + bo);
        }
#pragma unroll
        for (int nf = 0; nf < 8; ++nf) {
            int c = nf * 16 + lr;
            int bo = c * 256 + ((lq * 16 + ks * 64) ^ ((c & 7) << 4));
            short8 b = *(const short8*)((const char*)Ws + bo);
            acc[0][nf] = __builtin_amdgcn_mfma_f32_16x16x32_bf16(a[0], b, acc[0][nf], 0, 0, 0);
            acc[1][nf] = __builtin_amdgcn_mfma_f32_16x16x32_bf16(a[1], b, acc[1][nf], 0, 0, 0);
        }
    }

#pragma unroll
    for (int m = 0; m < 2; ++m) {
#pragma unroll
        for (int j = 0; j < 4; ++j) {
            int r = row0 + woff + m * 16 + lq * 4 + j;
            if (r < n) {
                float d = dinv[r];
#pragma unroll
                for (int nf = 0; nf < 8; ++nf)
                    G[(size_t)r * 128 + nf * 16 + lr] =
                        (unsigned short)bf16_rn(d * acc[m][nf][j]);
            }
        }
    }
}

// ---------------------------------------------------------------------------
// FUSED agg+swish+GEMM: block owns 64 nodes.
//  phase 1 (gather): 16-lane groups, 4 nodes/wave, 8-deep batches;
//     h[i] = swish(dinv[i]*(g[i]+sum_j g[j]) + b)  -> bf16 -> swizzled LDS.
//  phase 2 (MFMA): 64x OUT tile, 4 waves x 16 rows; epilogue dinv scale,
//     writes g_next bf16.
// ---------------------------------------------------------------------------
__device__ inline void acc8(float* a, uint4 u) {
    a[0] += bf_lo(u.x); a[1] += bf_hi(u.x);
    a[2] += bf_lo(u.y); a[3] += bf_hi(u.y);
    a[4] += bf_lo(u.z); a[5] += bf_hi(u.z);
    a[6] += bf_lo(u.w); a[7] += bf_hi(u.w);
}

template <int OUT>
__global__ __launch_bounds__(256, 4) void agg_gemm_k(
    const uint4* __restrict__ G4,            // [n][16] uint4 (128 bf16 cols)
    const int* __restrict__ rp,
    const int* __restrict__ col,
    const float* __restrict__ dinv,
    const float* __restrict__ bias,          // [128] agg bias (prev layer)
    const unsigned short* __restrict__ Wt,   // [OUT][128] bf16
    unsigned short* __restrict__ Gn,         // [n][OUT] bf16 out
    int n) {
    constexpr int NF = OUT / 16;
    __shared__ unsigned short lds[(64 + OUT) * 128];
    unsigned short* As = lds;                // 64 rows x 256B (swizzled)
    unsigned short* Ws = lds + 64 * 128;     // OUT rows x 256B (swizzled)

    const int tid = threadIdx.x;
    const int base = blockIdx.x * 64;
    const int sl = tid & 15;                 // 16B slice within row

    // ---- phase 1: gather + swish -> LDS (4 sequential node sub-rounds) ----
    const float4 bl = *(const float4*)&bias[sl * 8];
    const float4 bh = *(const float4*)&bias[sl * 8 + 4];
#pragma unroll
    for (int q = 0; q < 4; ++q) {
        const int local = (tid >> 4) + q * 16;      // 0..63
        const int i = base + local;
        uint4 o = make_uint4(0, 0, 0, 0);
        if (i < n) {
            float a[8] = {0.f, 0.f, 0.f, 0.f, 0.f, 0.f, 0.f, 0.f};
            acc8(a, G4[(size_t)i * 16 + sl]);       // self-loop
            const int s = rp[i], e = rp[i + 1];
            int p = s;
            for (; p + 8 <= e; p += 8) {
                uint4 v[8];
#pragma unroll
                for (int k = 0; k < 8; ++k) {
                    int j = col[p + k];
                    v[k] = G4[(size_t)j * 16 + sl];
                }
#pragma unroll
                for (int k = 0; k < 8; ++k) acc8(a, v[k]);
            }
            if (p < e) {                            // one clamped tail batch
                const int m = e - p;                // 1..7
                uint4 v[8];
#pragma unroll
                for (int k = 0; k < 8; ++k) {
                    int j = col[min(p + k, e - 1)];
                    v[k] = G4[(size_t)j * 16 + sl];
                }
#pragma unroll
                for (int k = 0; k < 8; ++k)
                    if (k < m) acc8(a, v[k]);
            }
            const float d = dinv[i];
            float r[8];
            r[0] = d * a[0] + bl.x; r[1] = d * a[1] + bl.y;
            r[2] = d * a[2] + bl.z; r[3] = d * a[3] + bl.w;
            r[4] = d * a[4] + bh.x; r[5] = d * a[5] + bh.y;
            r[6] = d * a[6] + bh.z; r[7] = d * a[7] + bh.w;
#pragma unroll
            for (int k = 0; k < 8; ++k) r[k] = r[k] / (1.f + expf(-r[k]));
            o.x = bf16_rn(r[0]) | (bf16_rn(r[1]) << 16);
            o.y = bf16_rn(r[2]) | (bf16_rn(r[3]) << 16);
            o.z = bf16_rn(r[4]) | (bf16_rn(r[5]) << 16);
            o.w = bf16_rn(r[6]) | (bf16_rn(r[7]) << 16);
        }
        int bo = local * 256 + ((sl * 16) ^ ((local & 7) << 4));
        *(uint4*)((char*)As + bo) = o;
    }

    // ---- stage W tile ----
#pragma unroll
    for (int p = 0; p < OUT / 16; ++p) {
        int id = p * 256 + tid;
        int r = id >> 4, c = id & 15;
        uint4 v = *(const uint4*)&Wt[(size_t)r * 128 + c * 8];
        int bo = r * 256 + ((c * 16) ^ ((r & 7) << 4));
        *(uint4*)((char*)Ws + bo) = v;
    }
    __syncthreads();

    // ---- phase 2: MFMA 64 x OUT, 4 waves x 16 rows ----
    const int wid = tid >> 6, lane = tid & 63;
    const int lq = lane >> 4, lr = lane & 15;
    const int woff = wid * 16;

    f32x4 acc[NF] = {};
#pragma unroll
    for (int ks = 0; ks < 4; ++ks) {
        int r = woff + lr;
        int bo = r * 256 + ((lq * 16 + ks * 64) ^ ((r & 7) << 4));
        short8 a = *(const short8*)((const char*)As + bo);
#pragma unroll
        for (int nf = 0; nf < NF; ++nf) {
            int c = nf * 16 + lr;
            int wo = c * 256 + ((lq * 16 + ks * 64) ^ ((c & 7) << 4));
            short8 b = *(const short8*)((const char*)Ws + wo);
            acc[nf] = __builtin_amdgcn_mfma_f32_16x16x32_bf16(a, b, acc[nf], 0, 0, 0);
        }
    }

#pragma unroll
    for (int j = 0; j < 4; ++j) {
        int r = base + woff + lq * 4 + j;
        if (r < n) {
            float d = dinv[r];
#pragma unroll
            for (int nf = 0; nf < NF; ++nf)
                Gn[(size_t)r * OUT + nf * 16 + lr] =
                    (unsigned short)bf16_rn(d * acc[nf][j]);
        }
    }
}

// ---------------------------------------------------------------------------
// Final aggregation (OUT=64) + log_softmax: 16-lane group per node, lane
// slice = uint2 (4 bf16 classes).  Group-local shuffle reduction (xor<16).
// ---------------------------------------------------------------------------
__global__ __launch_bounds__(512, 4) void agg_lsm_k(const uint2* __restrict__ G2,
                                                    const int* __restrict__ rp,
                                                    const int* __restrict__ col,
                                                    const float* __restrict__ dinv,
                                                    const float* __restrict__ bias,
                                                    float* __restrict__ out, int n) {
    const int i = (blockIdx.x * blockDim.x + threadIdx.x) >> 4;   // node
    const int sl = threadIdx.x & 15;                              // 8B slice
    if (i >= n) return;

    float a[4] = {0.f, 0.f, 0.f, 0.f};
    {
        uint2 u = G2[(size_t)i * 16 + sl];
        a[0] += bf_lo(u.x); a[1] += bf_hi(u.x);
        a[2] += bf_lo(u.y); a[3] += bf_hi(u.y);
    }
    const int s = rp[i], e = rp[i + 1];
    int p = s;
    for (; p + 8 <= e; p += 8) {
        uint2 v[8];
#pragma unroll
        for (int k = 0; k < 8; ++k) {
            int j = col[p + k];
            v[k] = G2[(size_t)j * 16 + sl];
        }
#pragma unroll
        for (int k = 0; k < 8; ++k) {
            a[0] += bf_lo(v[k].x); a[1] += bf_hi(v[k].x);
            a[2] += bf_lo(v[k].y); a[3] += bf_hi(v[k].y);
        }
    }
    if (p < e) {
        const int m = e - p;
        uint2 v[8];
#pragma unroll
        for (int k = 0; k < 8; ++k) {
            int j = col[min(p + k, e - 1)];
            v[k] = G2[(size_t)j * 16 + sl];
        }
#pragma unroll
        for (int k = 0; k < 8; ++k)
            if (k < m) {
                a[0] += bf_lo(v[k].x); a[1] += bf_hi(v[k].x);
                a[2] += bf_lo(v[k].y); a[3] += bf_hi(v[k].y);
            }
    }

    const float d = dinv[i];
    const float4 bv = *(const float4*)&bias[sl * 4];
    float lg[4];
    lg[0] = d * a[0] + bv.x; lg[1] = d * a[1] + bv.y;
    lg[2] = d * a[2] + bv.z; lg[3] = d * a[3] + bv.w;

    float m0 = fmaxf(fmaxf(lg[0], lg[1]), fmaxf(lg[2], lg[3]));
#pragma unroll
    for (int off = 1; off < 16; off <<= 1) m0 = fmaxf(m0, __shfl_xor(m0, off));
    float es = expf(lg[0] - m0) + expf(lg[1] - m0) +
               expf(lg[2] - m0) + expf(lg[3] - m0);
#pragma unroll
    for (int off = 1; off < 16; off <<= 1) es += __shfl_xor(es, off);
    const float lse = m0 + logf(es);
    float4 o;
    o.x = lg[0] - lse; o.y = lg[1] - lse; o.z = lg[2] - lse; o.w = lg[3] - lse;
    *(float4*)&out[(size_t)i * 64 + sl * 4] = o;
}

extern "C" void kernel_launch(void* const* d_in, const int* in_sizes, int n_in,
                              void* d_out, int out_size, void* d_ws, size_t ws_size,
                              hipStream_t stream) {
    const float* x = (const float*)d_in[0];
    const int* ei = (const int*)d_in[1];
    const float* W0 = (const float*)d_in[2];
    const float* b0 = (const float*)d_in[3];
    const float* W1 = (const float*)d_in[4];
    const float* b1 = (const float*)d_in[5];
    const float* W2 = (const float*)d_in[6];
    const float* b2 = (const float*)d_in[7];
    float* out = (float*)d_out;

    const int n = in_sizes[0] / 128;
    const int e = in_sizes[1] / 2;
    const int* src = ei;
    const int* dst = ei + e;

    char* ws = (char*)d_ws;
    size_t off = 0;
    auto alloc = [&](size_t bytes) -> void* {
        void* p = ws + off;
        off += (bytes + 255) & ~(size_t)255;
        return p;
    };
    int* bcnt = (int*)alloc(MAX_BUCKETS * 4 * 2);  // bcnt[64] | scur[64]
    int* scur = bcnt + MAX_BUCKETS;
    int* rp = (int*)alloc((size_t)(n + 1) * 4);    // CSR row_ptr
    float* dinv = (float*)alloc((size_t)n * 4);
    int* col = (int*)alloc((size_t)e * 4);         // CSR col (src per dst)
    unsigned* pairs = (unsigned*)alloc((size_t)e * 4);  // packed (src<<10|ldst)
    unsigned short* wt = (unsigned short*)alloc(40960 * 2);  // w0t|w1t|w2t
    unsigned short* ga = (unsigned short*)alloc((size_t)n * 256);  // g (128 cols)
    unsigned short* gb = (unsigned short*)alloc((size_t)n * 256);  // g' / g''

    unsigned short* w0t = wt;
    unsigned short* w1t = wt + 16384;
    unsigned short* w2t = wt + 32768;

    hipMemsetAsync(bcnt, 0, MAX_BUCKETS * 4 * 2, stream);
    prep_k<<<CVT_BLOCKS + (e + 4095) / 4096, 256, 0, stream>>>(dst, e, bcnt,
                                                               W0, W1, W2, wt);
    scatter_k<<<(e + 8191) / 8192, 512, 0, stream>>>(src, dst, e, bcnt, scur, pairs);
    const int nbuck = (n + NODES_PER_BUCKET - 1) / NODES_PER_BUCKET;  // 49
    build_k<<<nbuck, 1024, 0, stream>>>(pairs, bcnt, n, e, rp, dinv, col);

    const int gb128 = (n + 127) / 128;             // gemm0 blocks
    const int fb = (n + 63) / 64;                  // fused blocks (64 nodes)
    const int ab = (n + 31) / 32;                  // lsm blocks (32 nodes)

    // g0 = dinv.*(x@W0)
    mfma_gemm0_k<<<gb128, 256, 0, stream>>>(x, w0t, dinv, ga, n);
    // g1 = dinv.*(swish(agg(g0)+b0) @ W1)
    agg_gemm_k<128><<<fb, 256, 0, stream>>>((const uint4*)ga, rp, col, dinv, b0,
                                            w1t, gb, n);
    // g2 = dinv.*(swish(agg(g1)+b1) @ W2)   [n x 64]
    agg_gemm_k<64><<<fb, 256, 0, stream>>>((const uint4*)gb, rp, col, dinv, b1,
                                           w2t, ga, n);
    // out = log_softmax(agg(g2) + b2)
    agg_lsm_k<<<ab, 512, 0, stream>>>((const uint2*)ga, rp, col, dinv, b2, out, n);
}